// Round 1
// baseline (1195.054 us; speedup 1.0000x reference)
//
#include <hip/hip_runtime.h>
#include <math.h>

#define BB 8
#define NN 1024
#define IND 128
#define DD 32
#define HH 8

// ---------------------------------------------------------------------------
// ws layout:
//   Q [B,H,N,D] f32   (2M floats)
//   K [B,H,N,D] f32
//   V [B,H,N,D] f32
//   A8 [B,N,N] u8     (8.4 MB)
//   sums[4] double, cnt[2] u64
// ---------------------------------------------------------------------------

__global__ __launch_bounds__(256) void proj_kernel(
    const float* __restrict__ h,
    const float* __restrict__ Wq, const float* __restrict__ bq,
    const float* __restrict__ Wk, const float* __restrict__ bk,
    const float* __restrict__ Wv, const float* __restrict__ bv,
    float* __restrict__ Q, float* __restrict__ K, float* __restrict__ V)
{
    // grid (12, 128): 12 col-blocks of 64 (768 total outs), 128 row-blocks of 64
    const int cb = blockIdx.x;
    const int rb = blockIdx.y;
    const int t  = threadIdx.x;

    __shared__ float Xs[64][IND + 1];   // stride 129: 2-way max conflict
    __shared__ float Ws[64][IND + 1];

    const int which = cb >> 2;            // 0=q 1=k 2=v
    const int c0    = (cb & 3) * 64;      // col offset within 256
    const float* Wsrc = (which == 0) ? Wq : (which == 1) ? Wk : Wv;
    const float* bsrc = (which == 0) ? bq : (which == 1) ? bk : bv;
    float* Out        = (which == 0) ? Q  : (which == 1) ? K  : V;

    // stage 64x128 of X and W (2048 float4 each, 8 per thread)
    #pragma unroll
    for (int i = 0; i < 8; ++i) {
        int e = (i * 256 + t) * 4;
        int r = e >> 7;        // /128
        int c = e & 127;
        float4 x = *(const float4*)(&h[(size_t)(rb * 64 + r) * IND + c]);
        Xs[r][c] = x.x; Xs[r][c + 1] = x.y; Xs[r][c + 2] = x.z; Xs[r][c + 3] = x.w;
        float4 w = *(const float4*)(&Wsrc[(size_t)(c0 + r) * IND + c]);
        Ws[r][c] = w.x; Ws[r][c + 1] = w.y; Ws[r][c + 2] = w.z; Ws[r][c + 3] = w.w;
    }
    __syncthreads();

    const int tr = (t >> 4) * 4;
    const int tc = (t & 15) * 4;
    float acc[4][4] = {};
    #pragma unroll 4
    for (int k = 0; k < IND; ++k) {
        float a0 = Xs[tr + 0][k], a1 = Xs[tr + 1][k], a2 = Xs[tr + 2][k], a3 = Xs[tr + 3][k];
        float w0 = Ws[tc + 0][k], w1 = Ws[tc + 1][k], w2 = Ws[tc + 2][k], w3 = Ws[tc + 3][k];
        acc[0][0] = fmaf(a0, w0, acc[0][0]); acc[0][1] = fmaf(a0, w1, acc[0][1]);
        acc[0][2] = fmaf(a0, w2, acc[0][2]); acc[0][3] = fmaf(a0, w3, acc[0][3]);
        acc[1][0] = fmaf(a1, w0, acc[1][0]); acc[1][1] = fmaf(a1, w1, acc[1][1]);
        acc[1][2] = fmaf(a1, w2, acc[1][2]); acc[1][3] = fmaf(a1, w3, acc[1][3]);
        acc[2][0] = fmaf(a2, w0, acc[2][0]); acc[2][1] = fmaf(a2, w1, acc[2][1]);
        acc[2][2] = fmaf(a2, w2, acc[2][2]); acc[2][3] = fmaf(a2, w3, acc[2][3]);
        acc[3][0] = fmaf(a3, w0, acc[3][0]); acc[3][1] = fmaf(a3, w1, acc[3][1]);
        acc[3][2] = fmaf(a3, w2, acc[3][2]); acc[3][3] = fmaf(a3, w3, acc[3][3]);
    }

    #pragma unroll
    for (int i = 0; i < 4; ++i) {
        int r = rb * 64 + tr + i;            // global row in [0, 8192)
        int bb = r >> 10, n = r & 1023;
        #pragma unroll
        for (int j = 0; j < 4; ++j) {
            int o = tc + j + c0;             // [0,256) within this W
            int hh = o >> 5, dd = o & 31;
            Out[(((size_t)bb * HH + hh) * NN + n) * DD + dd] = acc[i][j] + bsrc[o];
        }
    }
}

// pack A (int32 0..5) -> u8, and count m1 (A==1), m2 (A>1) exactly
__global__ __launch_bounds__(256) void pack_kernel(
    const int* __restrict__ A, unsigned char* __restrict__ A8,
    unsigned long long* __restrict__ cnt)
{
    size_t idx = ((size_t)blockIdx.x * 256 + threadIdx.x) * 4;   // exact: 8192 blocks
    int4 a = *(const int4*)&A[idx];
    unsigned packed = (unsigned)(a.x & 0xff) | ((unsigned)(a.y & 0xff) << 8) |
                      ((unsigned)(a.z & 0xff) << 16) | ((unsigned)(a.w & 0xff) << 24);
    *(unsigned*)&A8[idx] = packed;
    unsigned c1 = (a.x == 1) + (a.y == 1) + (a.z == 1) + (a.w == 1);
    unsigned c2 = (a.x > 1) + (a.y > 1) + (a.z > 1) + (a.w > 1);
    #pragma unroll
    for (int off = 32; off; off >>= 1) {
        c1 += __shfl_down(c1, off);
        c2 += __shfl_down(c2, off);
    }
    if ((threadIdx.x & 63) == 0) {
        atomicAdd(&cnt[0], (unsigned long long)c1);
        atomicAdd(&cnt[1], (unsigned long long)c2);
    }
}

#define KT 64   // key tile

__global__ __launch_bounds__(256) void attn_kernel(
    const float* __restrict__ Q, const float* __restrict__ Kg, const float* __restrict__ Vg,
    const unsigned char* __restrict__ A8,
    const int* __restrict__ lengths, const float* __restrict__ alpha,
    float* __restrict__ out, double* __restrict__ sums)
{
    // block: (b, h, 32-query tile); 256 threads = 32 q-rows x 8 lanes
    const int bid = blockIdx.x;
    const int qt = bid & 31;
    const int hh = (bid >> 5) & 7;
    const int b  = bid >> 8;
    const int t  = threadIdx.x;
    const int q     = t >> 3;   // local query row 0..31
    const int lane8 = t & 7;

    const int len = lengths[b];
    const float al = alpha[0];
    float atab[8];
    atab[0] = 1.f;
    #pragma unroll
    for (int i = 1; i < 8; ++i) atab[i] = atab[i - 1] * al;

    __shared__ float Ks[KT][36];            // stride 36: 8 row-strided b128 reads hit disjoint bank quads
    __shared__ float Vs[KT][36];
    __shared__ unsigned char As[32][KT];
    __shared__ float red[4][32];

    const int gq = qt * 32 + q;
    const size_t base = ((size_t)b * HH + hh) * NN * DD;

    // Q row -> registers, pre-scaled by 1/sqrt(D)
    const float scale = 0.17677669529663687f;   // 1/sqrt(32)
    float qr[32];
    const float* qptr = Q + base + (size_t)gq * DD;
    #pragma unroll
    for (int i = 0; i < 8; ++i) {
        float4 v4 = *(const float4*)(qptr + i * 4);
        qr[4 * i + 0] = v4.x * scale; qr[4 * i + 1] = v4.y * scale;
        qr[4 * i + 2] = v4.z * scale; qr[4 * i + 3] = v4.w * scale;
    }

    float m = -1e30f, l = 0.f;
    float acc[4] = {0.f, 0.f, 0.f, 0.f};
    float s_pre1 = 0.f, s_pre2 = 0.f, s_post1 = 0.f, s_post2 = 0.f;
    const int dsl = lane8 * 4;

    for (int j0 = 0; j0 < NN; j0 += KT) {
        __syncthreads();
        // stage K,V tiles (KT x 32 each)
        #pragma unroll
        for (int i = 0; i < 2; ++i) {
            int e = (i * 256 + t) * 4;
            int r = e >> 5;
            int c = e & 31;
            *(float4*)&Ks[r][c] = *(const float4*)(Kg + base + (size_t)(j0 + r) * DD + c);
            *(float4*)&Vs[r][c] = *(const float4*)(Vg + base + (size_t)(j0 + r) * DD + c);
        }
        // stage A8 tile: 32 x 64 bytes
        {
            int r = t >> 3;
            int c = (t & 7) * 8;
            *(unsigned long long*)&As[r][c] =
                *(const unsigned long long*)(A8 + ((size_t)b * NN + (qt * 32 + r)) * NN + j0 + c);
        }
        __syncthreads();

        // scores: lane owns keys j = e*8 + lane8
        float s[8];
        #pragma unroll
        for (int e = 0; e < 8; ++e) {
            int j = e * 8 + lane8;
            float dot = 0.f;
            #pragma unroll
            for (int i = 0; i < 8; ++i) {
                float4 kv = *(const float4*)&Ks[j][i * 4];
                dot = fmaf(qr[4 * i + 0], kv.x, dot);
                dot = fmaf(qr[4 * i + 1], kv.y, dot);
                dot = fmaf(qr[4 * i + 2], kv.z, dot);
                dot = fmaf(qr[4 * i + 3], kv.w, dot);
            }
            s[e] = (j0 + j < len) ? dot : -INFINITY;
        }

        // tile max across my 8 keys, then across the 8-lane group
        float tmax = s[0];
        #pragma unroll
        for (int e = 1; e < 8; ++e) tmax = fmaxf(tmax, s[e]);
        #pragma unroll
        for (int off = 1; off < 8; off <<= 1) tmax = fmaxf(tmax, __shfl_xor(tmax, off, 8));

        float mnew = fmaxf(m, tmax);                 // -inf tile leaves m unchanged (finite)
        float sc = __expf(m - mnew);                 // exp(0)=1 on no-op
        l *= sc;
        acc[0] *= sc; acc[1] *= sc; acc[2] *= sc; acc[3] *= sc;
        s_pre1 *= sc; s_pre2 *= sc; s_post1 *= sc; s_post2 *= sc;
        m = mnew;

        float p[8];
        #pragma unroll
        for (int e = 0; e < 8; ++e) {
            int j = e * 8 + lane8;
            float pe = __expf(s[e] - m);             // -inf -> 0
            l += pe;
            int a = As[q][j];
            float w = atab[a & 7];
            float pw = pe * w;
            if (a == 1) { s_pre1 += pe; s_post1 += pw; }
            else if (a > 1) { s_pre2 += pe; s_post2 += pw; }
            p[e] = pw;                                // PV uses post-phi attention
        }

        // PV: broadcast p within 8-lane group; each lane owns d-slice dsl..dsl+3
        #pragma unroll
        for (int e = 0; e < 8; ++e) {
            #pragma unroll
            for (int src = 0; src < 8; ++src) {
                float pb = __shfl(p[e], src, 8);
                int j = e * 8 + src;
                float4 vv = *(const float4*)&Vs[j][dsl];
                acc[0] = fmaf(pb, vv.x, acc[0]);
                acc[1] = fmaf(pb, vv.y, acc[1]);
                acc[2] = fmaf(pb, vv.z, acc[2]);
                acc[3] = fmaf(pb, vv.w, acc[3]);
            }
        }
    }

    // finalize row: L = sum(l) over 8 lanes
    float L = l;
    #pragma unroll
    for (int off = 1; off < 8; off <<= 1) L += __shfl_xor(L, off, 8);
    const float inv = (gq < len) ? (1.f / L) : 0.f;   // zero padded query rows

    float4 o4 = make_float4(acc[0] * inv, acc[1] * inv, acc[2] * inv, acc[3] * inv);
    *(float4*)&out[base + (size_t)gq * DD + dsl] = o4;

    float v1 = s_pre1 * inv, v2 = s_pre2 * inv, v3 = s_post1 * inv, v4 = s_post2 * inv;
    #pragma unroll
    for (int off = 1; off < 8; off <<= 1) {
        v1 += __shfl_xor(v1, off, 8);
        v2 += __shfl_xor(v2, off, 8);
        v3 += __shfl_xor(v3, off, 8);
        v4 += __shfl_xor(v4, off, 8);
    }
    __syncthreads();
    if (lane8 == 0) { red[0][q] = v1; red[1][q] = v2; red[2][q] = v3; red[3][q] = v4; }
    __syncthreads();
    if (t < 4) {
        float s = 0.f;
        #pragma unroll
        for (int i = 0; i < 32; ++i) s += red[t][i];
        atomicAdd(&sums[t], (double)s);
    }
}

__global__ void fin_kernel(const double* __restrict__ sums,
                           const unsigned long long* __restrict__ cnt,
                           float* __restrict__ outtail)
{
    if (threadIdx.x == 0) {
        double c1 = (double)(cnt[0] * (unsigned long long)HH);
        double c2 = (double)(cnt[1] * (unsigned long long)HH);
        outtail[0] = (float)(sums[0] / c1);
        outtail[1] = (float)(sums[1] / c2);
        outtail[2] = (float)(sums[2] / c1);
        outtail[3] = (float)(sums[3] / c2);
    }
}

extern "C" void kernel_launch(void* const* d_in, const int* in_sizes, int n_in,
                              void* d_out, int out_size, void* d_ws, size_t ws_size,
                              hipStream_t stream)
{
    const float* h   = (const float*)d_in[0];
    const int* A     = (const int*)d_in[1];
    const int* lens  = (const int*)d_in[2];
    const float* alp = (const float*)d_in[3];
    const float* Wq  = (const float*)d_in[4];
    const float* bq  = (const float*)d_in[5];
    const float* Wk  = (const float*)d_in[6];
    const float* bk  = (const float*)d_in[7];
    const float* Wv  = (const float*)d_in[8];
    const float* bv  = (const float*)d_in[9];

    float* outF = (float*)d_out;

    const size_t qkv = (size_t)BB * HH * NN * DD;    // 2,097,152 floats
    float* Qw = (float*)d_ws;
    float* Kw = Qw + qkv;
    float* Vw = Kw + qkv;
    unsigned char* A8 = (unsigned char*)(Vw + qkv);
    double* sums = (double*)(A8 + (size_t)BB * NN * NN);
    unsigned long long* cnt = (unsigned long long*)(sums + 4);

    hipMemsetAsync(sums, 0, 4 * sizeof(double) + 2 * sizeof(unsigned long long), stream);

    proj_kernel<<<dim3(12, 128), 256, 0, stream>>>(h, Wq, bq, Wk, bk, Wv, bv, Qw, Kw, Vw);
    pack_kernel<<<(BB * NN * NN) / (256 * 4), 256, 0, stream>>>(A, A8, cnt);
    attn_kernel<<<BB * HH * (NN / 32), 256, 0, stream>>>(Qw, Kw, Vw, A8, lens, alp, outF, sums);
    fin_kernel<<<1, 64, 0, stream>>>(sums, cnt, outF + qkv);
}

// Round 2
// 410.841 us; speedup vs baseline: 2.9088x; 2.9088x over previous
//
#include <hip/hip_runtime.h>
#include <math.h>

#define BB 8
#define NN 1024
#define IND 128
#define DD 32
#define HH 8

// ---------------------------------------------------------------------------
// ws layout:
//   Q [B,H,N,D] f32   (2M floats)
//   K [B,H,N,D] f32
//   V [B,H,N,D] f32
//   A8 [B,N,N] u8     (8.4 MB)
//   sums[4] double, cnt[0] u64 @ +0, cnt[32] u64 @ +256B (parallel atomic chains)
// ---------------------------------------------------------------------------

__global__ __launch_bounds__(256) void proj_kernel(
    const float* __restrict__ h,
    const float* __restrict__ Wq, const float* __restrict__ bq,
    const float* __restrict__ Wk, const float* __restrict__ bk,
    const float* __restrict__ Wv, const float* __restrict__ bv,
    float* __restrict__ Q, float* __restrict__ K, float* __restrict__ V)
{
    // grid (12, 128): 12 col-blocks of 64 (768 total outs), 128 row-blocks of 64
    const int cb = blockIdx.x;
    const int rb = blockIdx.y;
    const int t  = threadIdx.x;

    __shared__ float Xs[64][IND + 1];   // stride 129: 2-way max conflict
    __shared__ float Ws[64][IND + 1];

    const int which = cb >> 2;            // 0=q 1=k 2=v
    const int c0    = (cb & 3) * 64;      // col offset within 256
    const float* Wsrc = (which == 0) ? Wq : (which == 1) ? Wk : Wv;
    const float* bsrc = (which == 0) ? bq : (which == 1) ? bk : bv;
    float* Out        = (which == 0) ? Q  : (which == 1) ? K  : V;

    // stage 64x128 of X and W (2048 float4 each, 8 per thread)
    #pragma unroll
    for (int i = 0; i < 8; ++i) {
        int e = (i * 256 + t) * 4;
        int r = e >> 7;        // /128
        int c = e & 127;
        float4 x = *(const float4*)(&h[(size_t)(rb * 64 + r) * IND + c]);
        Xs[r][c] = x.x; Xs[r][c + 1] = x.y; Xs[r][c + 2] = x.z; Xs[r][c + 3] = x.w;
        float4 w = *(const float4*)(&Wsrc[(size_t)(c0 + r) * IND + c]);
        Ws[r][c] = w.x; Ws[r][c + 1] = w.y; Ws[r][c + 2] = w.z; Ws[r][c + 3] = w.w;
    }
    __syncthreads();

    const int tr = (t >> 4) * 4;
    const int tc = (t & 15) * 4;
    float acc[4][4] = {};
    #pragma unroll 4
    for (int k = 0; k < IND; ++k) {
        float a0 = Xs[tr + 0][k], a1 = Xs[tr + 1][k], a2 = Xs[tr + 2][k], a3 = Xs[tr + 3][k];
        float w0 = Ws[tc + 0][k], w1 = Ws[tc + 1][k], w2 = Ws[tc + 2][k], w3 = Ws[tc + 3][k];
        acc[0][0] = fmaf(a0, w0, acc[0][0]); acc[0][1] = fmaf(a0, w1, acc[0][1]);
        acc[0][2] = fmaf(a0, w2, acc[0][2]); acc[0][3] = fmaf(a0, w3, acc[0][3]);
        acc[1][0] = fmaf(a1, w0, acc[1][0]); acc[1][1] = fmaf(a1, w1, acc[1][1]);
        acc[1][2] = fmaf(a1, w2, acc[1][2]); acc[1][3] = fmaf(a1, w3, acc[1][3]);
        acc[2][0] = fmaf(a2, w0, acc[2][0]); acc[2][1] = fmaf(a2, w1, acc[2][1]);
        acc[2][2] = fmaf(a2, w2, acc[2][2]); acc[2][3] = fmaf(a2, w3, acc[2][3]);
        acc[3][0] = fmaf(a3, w0, acc[3][0]); acc[3][1] = fmaf(a3, w1, acc[3][1]);
        acc[3][2] = fmaf(a3, w2, acc[3][2]); acc[3][3] = fmaf(a3, w3, acc[3][3]);
    }

    #pragma unroll
    for (int i = 0; i < 4; ++i) {
        int r = rb * 64 + tr + i;            // global row in [0, 8192)
        int bb = r >> 10, n = r & 1023;
        #pragma unroll
        for (int j = 0; j < 4; ++j) {
            int o = tc + j + c0;             // [0,256) within this W
            int hh = o >> 5, dd = o & 31;
            Out[(((size_t)bb * HH + hh) * NN + n) * DD + dd] = acc[i][j] + bsrc[o];
        }
    }
}

// pack A (int32 0..5) -> u8, and count m1 (A==1), m2 (A>1) exactly.
// R1 fix: 790us -> ~15us. Old version did 2 atomicAdds per wave (65536 atomics
// on one cache line -> serialized chain ~= 820us at ~30cyc/atomic). Now:
// grid-stride 1024 blocks, register counts -> wave shfl reduce -> LDS reduce
// -> 1 atomic per counter per block, counters 256B apart (separate L2 banks).
__global__ __launch_bounds__(256) void pack_kernel(
    const int* __restrict__ A, unsigned char* __restrict__ A8,
    unsigned long long* __restrict__ cnt)
{
    const int NT = (BB * NN * NN) / 4;                 // 2,097,152 int4s
    unsigned c1 = 0, c2 = 0;
    for (int idx = blockIdx.x * 256 + threadIdx.x; idx < NT; idx += gridDim.x * 256) {
        int4 a = *(const int4*)&A[(size_t)idx * 4];
        unsigned packed = (unsigned)(a.x & 0xff) | ((unsigned)(a.y & 0xff) << 8) |
                          ((unsigned)(a.z & 0xff) << 16) | ((unsigned)(a.w & 0xff) << 24);
        *(unsigned*)&A8[(size_t)idx * 4] = packed;
        c1 += (a.x == 1) + (a.y == 1) + (a.z == 1) + (a.w == 1);
        c2 += (a.x > 1) + (a.y > 1) + (a.z > 1) + (a.w > 1);
    }
    #pragma unroll
    for (int off = 32; off; off >>= 1) {
        c1 += __shfl_down(c1, off);
        c2 += __shfl_down(c2, off);
    }
    __shared__ unsigned r1[4], r2[4];
    const int wave = threadIdx.x >> 6;
    if ((threadIdx.x & 63) == 0) { r1[wave] = c1; r2[wave] = c2; }
    __syncthreads();
    if (threadIdx.x == 0) {
        unsigned long long t1 = (unsigned long long)r1[0] + r1[1] + r1[2] + r1[3];
        unsigned long long t2 = (unsigned long long)r2[0] + r2[1] + r2[2] + r2[3];
        atomicAdd(&cnt[0], t1);
        atomicAdd(&cnt[32], t2);   // 256B apart -> independent atomic chain
    }
}

#define KT 64   // key tile

__global__ __launch_bounds__(256) void attn_kernel(
    const float* __restrict__ Q, const float* __restrict__ Kg, const float* __restrict__ Vg,
    const unsigned char* __restrict__ A8,
    const int* __restrict__ lengths, const float* __restrict__ alpha,
    float* __restrict__ out, double* __restrict__ sums)
{
    // block: (b, h, 32-query tile); 256 threads = 32 q-rows x 8 lanes
    const int bid = blockIdx.x;
    const int qt = bid & 31;
    const int hh = (bid >> 5) & 7;
    const int b  = bid >> 8;
    const int t  = threadIdx.x;
    const int q     = t >> 3;   // local query row 0..31
    const int lane8 = t & 7;

    const int len = lengths[b];
    const float al = alpha[0];
    float atab[8];
    atab[0] = 1.f;
    #pragma unroll
    for (int i = 1; i < 8; ++i) atab[i] = atab[i - 1] * al;

    __shared__ float Ks[KT][36];            // stride 36: 8 row-strided b128 reads hit disjoint bank quads
    __shared__ float Vs[KT][36];
    __shared__ unsigned char As[32][KT];
    __shared__ float red[4][32];

    const int gq = qt * 32 + q;
    const size_t base = ((size_t)b * HH + hh) * NN * DD;

    // Q row -> registers, pre-scaled by 1/sqrt(D)
    const float scale = 0.17677669529663687f;   // 1/sqrt(32)
    float qr[32];
    const float* qptr = Q + base + (size_t)gq * DD;
    #pragma unroll
    for (int i = 0; i < 8; ++i) {
        float4 v4 = *(const float4*)(qptr + i * 4);
        qr[4 * i + 0] = v4.x * scale; qr[4 * i + 1] = v4.y * scale;
        qr[4 * i + 2] = v4.z * scale; qr[4 * i + 3] = v4.w * scale;
    }

    float m = -1e30f, l = 0.f;
    float acc[4] = {0.f, 0.f, 0.f, 0.f};
    float s_pre1 = 0.f, s_pre2 = 0.f, s_post1 = 0.f, s_post2 = 0.f;
    const int dsl = lane8 * 4;

    for (int j0 = 0; j0 < NN; j0 += KT) {
        __syncthreads();
        // stage K,V tiles (KT x 32 each)
        #pragma unroll
        for (int i = 0; i < 2; ++i) {
            int e = (i * 256 + t) * 4;
            int r = e >> 5;
            int c = e & 31;
            *(float4*)&Ks[r][c] = *(const float4*)(Kg + base + (size_t)(j0 + r) * DD + c);
            *(float4*)&Vs[r][c] = *(const float4*)(Vg + base + (size_t)(j0 + r) * DD + c);
        }
        // stage A8 tile: 32 x 64 bytes
        {
            int r = t >> 3;
            int c = (t & 7) * 8;
            *(unsigned long long*)&As[r][c] =
                *(const unsigned long long*)(A8 + ((size_t)b * NN + (qt * 32 + r)) * NN + j0 + c);
        }
        __syncthreads();

        // scores: lane owns keys j = e*8 + lane8
        float s[8];
        #pragma unroll
        for (int e = 0; e < 8; ++e) {
            int j = e * 8 + lane8;
            float dot = 0.f;
            #pragma unroll
            for (int i = 0; i < 8; ++i) {
                float4 kv = *(const float4*)&Ks[j][i * 4];
                dot = fmaf(qr[4 * i + 0], kv.x, dot);
                dot = fmaf(qr[4 * i + 1], kv.y, dot);
                dot = fmaf(qr[4 * i + 2], kv.z, dot);
                dot = fmaf(qr[4 * i + 3], kv.w, dot);
            }
            s[e] = (j0 + j < len) ? dot : -INFINITY;
        }

        // tile max across my 8 keys, then across the 8-lane group
        float tmax = s[0];
        #pragma unroll
        for (int e = 1; e < 8; ++e) tmax = fmaxf(tmax, s[e]);
        #pragma unroll
        for (int off = 1; off < 8; off <<= 1) tmax = fmaxf(tmax, __shfl_xor(tmax, off, 8));

        float mnew = fmaxf(m, tmax);                 // -inf tile leaves m unchanged (finite)
        float sc = __expf(m - mnew);                 // exp(0)=1 on no-op
        l *= sc;
        acc[0] *= sc; acc[1] *= sc; acc[2] *= sc; acc[3] *= sc;
        s_pre1 *= sc; s_pre2 *= sc; s_post1 *= sc; s_post2 *= sc;
        m = mnew;

        float p[8];
        #pragma unroll
        for (int e = 0; e < 8; ++e) {
            int j = e * 8 + lane8;
            float pe = __expf(s[e] - m);             // -inf -> 0
            l += pe;
            int a = As[q][j];
            float w = atab[a & 7];
            float pw = pe * w;
            if (a == 1) { s_pre1 += pe; s_post1 += pw; }
            else if (a > 1) { s_pre2 += pe; s_post2 += pw; }
            p[e] = pw;                                // PV uses post-phi attention
        }

        // PV: broadcast p within 8-lane group; each lane owns d-slice dsl..dsl+3
        #pragma unroll
        for (int e = 0; e < 8; ++e) {
            #pragma unroll
            for (int src = 0; src < 8; ++src) {
                float pb = __shfl(p[e], src, 8);
                int j = e * 8 + src;
                float4 vv = *(const float4*)&Vs[j][dsl];
                acc[0] = fmaf(pb, vv.x, acc[0]);
                acc[1] = fmaf(pb, vv.y, acc[1]);
                acc[2] = fmaf(pb, vv.z, acc[2]);
                acc[3] = fmaf(pb, vv.w, acc[3]);
            }
        }
    }

    // finalize row: L = sum(l) over 8 lanes
    float L = l;
    #pragma unroll
    for (int off = 1; off < 8; off <<= 1) L += __shfl_xor(L, off, 8);
    const float inv = (gq < len) ? (1.f / L) : 0.f;   // zero padded query rows

    float4 o4 = make_float4(acc[0] * inv, acc[1] * inv, acc[2] * inv, acc[3] * inv);
    *(float4*)&out[base + (size_t)gq * DD + dsl] = o4;

    float v1 = s_pre1 * inv, v2 = s_pre2 * inv, v3 = s_post1 * inv, v4 = s_post2 * inv;
    #pragma unroll
    for (int off = 1; off < 8; off <<= 1) {
        v1 += __shfl_xor(v1, off, 8);
        v2 += __shfl_xor(v2, off, 8);
        v3 += __shfl_xor(v3, off, 8);
        v4 += __shfl_xor(v4, off, 8);
    }
    __syncthreads();
    if (lane8 == 0) { red[0][q] = v1; red[1][q] = v2; red[2][q] = v3; red[3][q] = v4; }
    __syncthreads();
    if (t < 4) {
        float s = 0.f;
        #pragma unroll
        for (int i = 0; i < 32; ++i) s += red[t][i];
        atomicAdd(&sums[t], (double)s);
    }
}

__global__ void fin_kernel(const double* __restrict__ sums,
                           const unsigned long long* __restrict__ cnt,
                           float* __restrict__ outtail)
{
    if (threadIdx.x == 0) {
        double c1 = (double)(cnt[0] * (unsigned long long)HH);
        double c2 = (double)(cnt[32] * (unsigned long long)HH);
        outtail[0] = (float)(sums[0] / c1);
        outtail[1] = (float)(sums[1] / c2);
        outtail[2] = (float)(sums[2] / c1);
        outtail[3] = (float)(sums[3] / c2);
    }
}

extern "C" void kernel_launch(void* const* d_in, const int* in_sizes, int n_in,
                              void* d_out, int out_size, void* d_ws, size_t ws_size,
                              hipStream_t stream)
{
    const float* h   = (const float*)d_in[0];
    const int* A     = (const int*)d_in[1];
    const int* lens  = (const int*)d_in[2];
    const float* alp = (const float*)d_in[3];
    const float* Wq  = (const float*)d_in[4];
    const float* bq  = (const float*)d_in[5];
    const float* Wk  = (const float*)d_in[6];
    const float* bk  = (const float*)d_in[7];
    const float* Wv  = (const float*)d_in[8];
    const float* bv  = (const float*)d_in[9];

    float* outF = (float*)d_out;

    const size_t qkv = (size_t)BB * HH * NN * DD;    // 2,097,152 floats
    float* Qw = (float*)d_ws;
    float* Kw = Qw + qkv;
    float* Vw = Kw + qkv;
    unsigned char* A8 = (unsigned char*)(Vw + qkv);
    double* sums = (double*)(A8 + (size_t)BB * NN * NN);
    unsigned long long* cnt = (unsigned long long*)(sums + 4);

    // zero sums[4] + cnt region (cnt[0] and cnt[32] span 33 u64 = 264B)
    hipMemsetAsync(sums, 0, 4 * sizeof(double) + 33 * sizeof(unsigned long long), stream);

    proj_kernel<<<dim3(12, 128), 256, 0, stream>>>(h, Wq, bq, Wk, bk, Wv, bv, Qw, Kw, Vw);
    pack_kernel<<<1024, 256, 0, stream>>>(A, A8, cnt);
    attn_kernel<<<BB * HH * (NN / 32), 256, 0, stream>>>(Qw, Kw, Vw, A8, lens, alp, outF, sums);
    fin_kernel<<<1, 64, 0, stream>>>(sums, cnt, outF + qkv);
}

// Round 10
// 257.717 us; speedup vs baseline: 4.6371x; 1.5942x over previous
//
#include <hip/hip_runtime.h>
#include <math.h>

#define BB 8
#define NN 1024
#define IND 128
#define DD 32
#define HH 8
#define KT 64   // key tile
#define QT 64   // query rows per block

// ---------------------------------------------------------------------------
// ws layout:
//   Q [B,H,N,D] f32   (2M floats)
//   K [B,H,N,D] f32
//   V [B,H,N,D] f32
//   A8 [B,N,N] u8     (8.4 MB)
//   sums: double[128]  (4 used, spread 32 apart = 256B -> parallel atomic chains)
//   cnt:  u64[64]      (cnt[0], cnt[32])
// ---------------------------------------------------------------------------

__global__ __launch_bounds__(256) void proj_kernel(
    const float* __restrict__ h,
    const float* __restrict__ Wq, const float* __restrict__ bq,
    const float* __restrict__ Wk, const float* __restrict__ bk,
    const float* __restrict__ Wv, const float* __restrict__ bv,
    const int* __restrict__ lengths,
    float* __restrict__ Q, float* __restrict__ K, float* __restrict__ V)
{
    const int cb = blockIdx.x;
    const int rb = blockIdx.y;
    // R2: skip row-blocks entirely past this batch's length (outputs unused:
    // keys>=len are masked, padded q-rows are zeroed in attn)
    if (((rb & 15) * 64) >= lengths[rb >> 4]) return;

    const int t  = threadIdx.x;
    __shared__ float Xs[64][IND + 1];
    __shared__ float Ws[64][IND + 1];

    const int which = cb >> 2;            // 0=q 1=k 2=v
    const int c0    = (cb & 3) * 64;
    const float* Wsrc = (which == 0) ? Wq : (which == 1) ? Wk : Wv;
    const float* bsrc = (which == 0) ? bq : (which == 1) ? bk : bv;
    float* Out        = (which == 0) ? Q  : (which == 1) ? K  : V;

    #pragma unroll
    for (int i = 0; i < 8; ++i) {
        int e = (i * 256 + t) * 4;
        int r = e >> 7;
        int c = e & 127;
        float4 x = *(const float4*)(&h[(size_t)(rb * 64 + r) * IND + c]);
        Xs[r][c] = x.x; Xs[r][c + 1] = x.y; Xs[r][c + 2] = x.z; Xs[r][c + 3] = x.w;
        float4 w = *(const float4*)(&Wsrc[(size_t)(c0 + r) * IND + c]);
        Ws[r][c] = w.x; Ws[r][c + 1] = w.y; Ws[r][c + 2] = w.z; Ws[r][c + 3] = w.w;
    }
    __syncthreads();

    const int tr = (t >> 4) * 4;
    const int tc = (t & 15) * 4;
    float acc[4][4] = {};
    #pragma unroll 4
    for (int k = 0; k < IND; ++k) {
        float a0 = Xs[tr + 0][k], a1 = Xs[tr + 1][k], a2 = Xs[tr + 2][k], a3 = Xs[tr + 3][k];
        float w0 = Ws[tc + 0][k], w1 = Ws[tc + 1][k], w2 = Ws[tc + 2][k], w3 = Ws[tc + 3][k];
        acc[0][0] = fmaf(a0, w0, acc[0][0]); acc[0][1] = fmaf(a0, w1, acc[0][1]);
        acc[0][2] = fmaf(a0, w2, acc[0][2]); acc[0][3] = fmaf(a0, w3, acc[0][3]);
        acc[1][0] = fmaf(a1, w0, acc[1][0]); acc[1][1] = fmaf(a1, w1, acc[1][1]);
        acc[1][2] = fmaf(a1, w2, acc[1][2]); acc[1][3] = fmaf(a1, w3, acc[1][3]);
        acc[2][0] = fmaf(a2, w0, acc[2][0]); acc[2][1] = fmaf(a2, w1, acc[2][1]);
        acc[2][2] = fmaf(a2, w2, acc[2][2]); acc[2][3] = fmaf(a2, w3, acc[2][3]);
        acc[3][0] = fmaf(a3, w0, acc[3][0]); acc[3][1] = fmaf(a3, w1, acc[3][1]);
        acc[3][2] = fmaf(a3, w2, acc[3][2]); acc[3][3] = fmaf(a3, w3, acc[3][3]);
    }

    #pragma unroll
    for (int i = 0; i < 4; ++i) {
        int r = rb * 64 + tr + i;
        int bb = r >> 10, n = r & 1023;
        #pragma unroll
        for (int j = 0; j < 4; ++j) {
            int o = tc + j + c0;
            int hh = o >> 5, dd = o & 31;
            Out[(((size_t)bb * HH + hh) * NN + n) * DD + dd] = acc[i][j] + bsrc[o];
        }
    }
}

// pack A (int32 0..5) -> u8, and count m1 (A==1), m2 (A>1) exactly.
__global__ __launch_bounds__(256) void pack_kernel(
    const int* __restrict__ A, unsigned char* __restrict__ A8,
    unsigned long long* __restrict__ cnt)
{
    const int NT = (BB * NN * NN) / 4;
    unsigned c1 = 0, c2 = 0;
    for (int idx = blockIdx.x * 256 + threadIdx.x; idx < NT; idx += gridDim.x * 256) {
        int4 a = *(const int4*)&A[(size_t)idx * 4];
        unsigned packed = (unsigned)(a.x & 0xff) | ((unsigned)(a.y & 0xff) << 8) |
                          ((unsigned)(a.z & 0xff) << 16) | ((unsigned)(a.w & 0xff) << 24);
        *(unsigned*)&A8[(size_t)idx * 4] = packed;
        c1 += (a.x == 1) + (a.y == 1) + (a.z == 1) + (a.w == 1);
        c2 += (a.x > 1) + (a.y > 1) + (a.z > 1) + (a.w > 1);
    }
    #pragma unroll
    for (int off = 32; off; off >>= 1) {
        c1 += __shfl_down(c1, off);
        c2 += __shfl_down(c2, off);
    }
    __shared__ unsigned r1[4], r2[4];
    const int wave = threadIdx.x >> 6;
    if ((threadIdx.x & 63) == 0) { r1[wave] = c1; r2[wave] = c2; }
    __syncthreads();
    if (threadIdx.x == 0) {
        unsigned long long t1 = (unsigned long long)r1[0] + r1[1] + r1[2] + r1[3];
        unsigned long long t2 = (unsigned long long)r2[0] + r2[1] + r2[2] + r2[3];
        atomicAdd(&cnt[0], t1);
        atomicAdd(&cnt[32], t2);
    }
}

// R2 attn: 64 q-rows/block, 2 q-rows/thread (K/V b128 reads feed 8 FMA each),
// lane-local p with per-lane full-D partial acc (no per-tile shfl broadcast),
// length-based tile skip. 256 thr = 32 q-groups x 8 lanes; lane owns keys
// j = e*8+lane8 (strided => conflict-free vs stride-36 LDS pad).
// R8 fix: __exp2f is NOT a HIP device intrinsic (resolves to glibc host decl
// -> device compile error). Use exp2f (lowers to v_exp_f32 directly).
__global__ __launch_bounds__(256) void attn_kernel(
    const float* __restrict__ Q, const float* __restrict__ Kg, const float* __restrict__ Vg,
    const unsigned char* __restrict__ A8,
    const int* __restrict__ lengths, const float* __restrict__ alpha,
    float* __restrict__ out, double* __restrict__ sums)
{
    const int bid = blockIdx.x;
    const int qt = bid & 15;
    const int hh = (bid >> 4) & 7;
    const int b  = bid >> 7;
    const int t  = threadIdx.x;
    const int qg = t >> 3;        // 0..31
    const int lane8 = t & 7;

    const int len = lengths[b];
    const size_t base = ((size_t)b * HH + hh) * NN * DD;
    const int gq0 = qt * QT + qg;
    const int gq1 = gq0 + 32;

    if (qt * QT >= len) {         // fully padded q-block: write zeros, done
        float4 z = make_float4(0.f, 0.f, 0.f, 0.f);
        *(float4*)&out[base + (size_t)gq0 * DD + lane8 * 4] = z;
        *(float4*)&out[base + (size_t)gq1 * DD + lane8 * 4] = z;
        return;
    }

    __shared__ float Qs[QT][36];
    __shared__ float Ks[KT][36];
    __shared__ float Vs[KT][36];
    __shared__ unsigned char As[QT][80];
    __shared__ float red4[4][4];

    const float al  = alpha[0];
    const float l2a = __log2f(al);
    const float scale = 0.17677669529663687f;   // 1/sqrt(32)

    // permuted staging (r,c): quad = (r+c)%8 distinct per wave -> no write conflict
    const int sr = t >> 3;
    const int sc = ((t & 7) - sr) & 7;

    #pragma unroll
    for (int i = 0; i < 2; ++i) {
        int r = i * 32 + sr;
        float4 v = *(const float4*)&Q[base + (size_t)(qt * QT + r) * DD + sc * 4];
        v.x *= scale; v.y *= scale; v.z *= scale; v.w *= scale;
        *(float4*)&Qs[r][sc * 4] = v;
    }

    float m0 = -1e30f, m1 = -1e30f, l0 = 0.f, l1 = 0.f;
    float acc0[32], acc1[32];
    #pragma unroll
    for (int d = 0; d < 32; ++d) { acc0[d] = 0.f; acc1[d] = 0.f; }
    float pr0_1 = 0.f, pr0_2 = 0.f, po0_1 = 0.f, po0_2 = 0.f;
    float pr1_1 = 0.f, pr1_2 = 0.f, po1_1 = 0.f, po1_2 = 0.f;

    for (int j0 = 0; j0 < len; j0 += KT) {
        __syncthreads();
        #pragma unroll
        for (int i = 0; i < 2; ++i) {
            int r = i * 32 + sr;
            *(float4*)&Ks[r][sc * 4] = *(const float4*)&Kg[base + (size_t)(j0 + r) * DD + sc * 4];
            *(float4*)&Vs[r][sc * 4] = *(const float4*)&Vg[base + (size_t)(j0 + r) * DD + sc * 4];
        }
        {
            int r = t >> 2, c = (t & 3) * 16;
            *(int4*)&As[r][c] = *(const int4*)&A8[((size_t)b * NN + qt * QT + r) * NN + j0 + c];
        }
        __syncthreads();

        // QK^T: 64 K-b128 + 16 Q-b128 for 512 FMA
        float s0[8], s1[8];
        #pragma unroll
        for (int e = 0; e < 8; ++e) { s0[e] = 0.f; s1[e] = 0.f; }
        #pragma unroll
        for (int i = 0; i < 8; ++i) {
            float4 qa = *(const float4*)&Qs[qg][i * 4];
            float4 qb = *(const float4*)&Qs[qg + 32][i * 4];
            #pragma unroll
            for (int e = 0; e < 8; ++e) {
                float4 kv = *(const float4*)&Ks[e * 8 + lane8][i * 4];
                s0[e] = fmaf(qa.x, kv.x, s0[e]); s0[e] = fmaf(qa.y, kv.y, s0[e]);
                s0[e] = fmaf(qa.z, kv.z, s0[e]); s0[e] = fmaf(qa.w, kv.w, s0[e]);
                s1[e] = fmaf(qb.x, kv.x, s1[e]); s1[e] = fmaf(qb.y, kv.y, s1[e]);
                s1[e] = fmaf(qb.z, kv.z, s1[e]); s1[e] = fmaf(qb.w, kv.w, s1[e]);
            }
        }

        // mask + row max (local then 8-lane butterfly)
        float tm0 = -INFINITY, tm1 = -INFINITY;
        #pragma unroll
        for (int e = 0; e < 8; ++e) {
            bool valid = (j0 + e * 8 + lane8) < len;
            s0[e] = valid ? s0[e] : -INFINITY;
            s1[e] = valid ? s1[e] : -INFINITY;
            tm0 = fmaxf(tm0, s0[e]); tm1 = fmaxf(tm1, s1[e]);
        }
        #pragma unroll
        for (int off = 1; off < 8; off <<= 1) {
            tm0 = fmaxf(tm0, __shfl_xor(tm0, off, 8));
            tm1 = fmaxf(tm1, __shfl_xor(tm1, off, 8));
        }
        if (tm0 > m0) {            // defer-max: skip rescale when max unchanged
            float scl = __expf(m0 - tm0);
            l0 *= scl; pr0_1 *= scl; pr0_2 *= scl; po0_1 *= scl; po0_2 *= scl;
            #pragma unroll
            for (int d = 0; d < 32; ++d) acc0[d] *= scl;
            m0 = tm0;
        }
        if (tm1 > m1) {
            float scl = __expf(m1 - tm1);
            l1 *= scl; pr1_1 *= scl; pr1_2 *= scl; po1_1 *= scl; po1_2 *= scl;
            #pragma unroll
            for (int d = 0; d < 32; ++d) acc1[d] *= scl;
            m1 = tm1;
        }

        // p = exp(s-m); adjacency weight alpha^a = exp2(a*log2(alpha))
        #pragma unroll
        for (int e = 0; e < 8; ++e) {
            int j = e * 8 + lane8;
            float pe0 = __expf(s0[e] - m0);
            float pe1 = __expf(s1[e] - m1);
            l0 += pe0; l1 += pe1;
            int a0 = As[qg][j], a1 = As[qg + 32][j];
            float w0 = exp2f((float)a0 * l2a);
            float w1 = exp2f((float)a1 * l2a);
            float pw0 = pe0 * w0, pw1 = pe1 * w1;
            pr0_1 += (a0 == 1) ? pe0 : 0.f;  pr0_2 += (a0 > 1) ? pe0 : 0.f;
            po0_1 += (a0 == 1) ? pw0 : 0.f;  po0_2 += (a0 > 1) ? pw0 : 0.f;
            pr1_1 += (a1 == 1) ? pe1 : 0.f;  pr1_2 += (a1 > 1) ? pe1 : 0.f;
            po1_1 += (a1 == 1) ? pw1 : 0.f;  po1_2 += (a1 > 1) ? pw1 : 0.f;
            s0[e] = pw0; s1[e] = pw1;        // reuse as post-phi p
        }

        // PV: lane-local partial acc over full D; 64 V-b128 for 512 FMA
        #pragma unroll
        for (int e = 0; e < 8; ++e) {
            float pw0 = s0[e], pw1 = s1[e];
            #pragma unroll
            for (int i = 0; i < 8; ++i) {
                float4 vv = *(const float4*)&Vs[e * 8 + lane8][i * 4];
                acc0[i * 4 + 0] = fmaf(pw0, vv.x, acc0[i * 4 + 0]);
                acc0[i * 4 + 1] = fmaf(pw0, vv.y, acc0[i * 4 + 1]);
                acc0[i * 4 + 2] = fmaf(pw0, vv.z, acc0[i * 4 + 2]);
                acc0[i * 4 + 3] = fmaf(pw0, vv.w, acc0[i * 4 + 3]);
                acc1[i * 4 + 0] = fmaf(pw1, vv.x, acc1[i * 4 + 0]);
                acc1[i * 4 + 1] = fmaf(pw1, vv.y, acc1[i * 4 + 1]);
                acc1[i * 4 + 2] = fmaf(pw1, vv.z, acc1[i * 4 + 2]);
                acc1[i * 4 + 3] = fmaf(pw1, vv.w, acc1[i * 4 + 3]);
            }
        }
    }

    // row denominators
    #pragma unroll
    for (int off = 1; off < 8; off <<= 1) {
        l0 += __shfl_xor(l0, off, 8);
        l1 += __shfl_xor(l1, off, 8);
    }
    const float inv0 = (gq0 < len) ? 1.f / l0 : 0.f;
    const float inv1 = (gq1 < len) ? 1.f / l1 : 0.f;

    // once-per-block butterfly reduce of partial acc across the 8 lanes
    #pragma unroll
    for (int off = 1; off < 8; off <<= 1) {
        #pragma unroll
        for (int d = 0; d < 32; ++d) {
            acc0[d] += __shfl_xor(acc0[d], off, 8);
            acc1[d] += __shfl_xor(acc1[d], off, 8);
        }
    }
    if (lane8 == 0) {             // all lanes hold full sums; lane 0 writes rows
        #pragma unroll
        for (int i = 0; i < 8; ++i) {
            *(float4*)&out[base + (size_t)gq0 * DD + i * 4] =
                make_float4(acc0[i * 4 + 0] * inv0, acc0[i * 4 + 1] * inv0,
                            acc0[i * 4 + 2] * inv0, acc0[i * 4 + 3] * inv0);
            *(float4*)&out[base + (size_t)gq1 * DD + i * 4] =
                make_float4(acc1[i * 4 + 0] * inv1, acc1[i * 4 + 1] * inv1,
                            acc1[i * 4 + 2] * inv1, acc1[i * 4 + 3] * inv1);
        }
    }

    // scalar sums: full-wave butterfly -> per-wave -> LDS -> 4 spread atomics
    float v1 = pr0_1 * inv0 + pr1_1 * inv1;
    float v2 = pr0_2 * inv0 + pr1_2 * inv1;
    float v3 = po0_1 * inv0 + po1_1 * inv1;
    float v4 = po0_2 * inv0 + po1_2 * inv1;
    #pragma unroll
    for (int off = 1; off < 64; off <<= 1) {
        v1 += __shfl_xor(v1, off);
        v2 += __shfl_xor(v2, off);
        v3 += __shfl_xor(v3, off);
        v4 += __shfl_xor(v4, off);
    }
    const int wv = t >> 6;
    if ((t & 63) == 0) { red4[0][wv] = v1; red4[1][wv] = v2; red4[2][wv] = v3; red4[3][wv] = v4; }
    __syncthreads();
    if (t < 4) {
        float s = red4[t][0] + red4[t][1] + red4[t][2] + red4[t][3];
        atomicAdd(&sums[t * 32], (double)s);   // 256B apart: parallel chains
    }
}

__global__ void fin_kernel(const double* __restrict__ sums,
                           const unsigned long long* __restrict__ cnt,
                           float* __restrict__ outtail)
{
    if (threadIdx.x == 0) {
        double c1 = (double)(cnt[0] * (unsigned long long)HH);
        double c2 = (double)(cnt[32] * (unsigned long long)HH);
        outtail[0] = (float)(sums[0]  / c1);
        outtail[1] = (float)(sums[32] / c2);
        outtail[2] = (float)(sums[64] / c1);
        outtail[3] = (float)(sums[96] / c2);
    }
}

extern "C" void kernel_launch(void* const* d_in, const int* in_sizes, int n_in,
                              void* d_out, int out_size, void* d_ws, size_t ws_size,
                              hipStream_t stream)
{
    const float* h   = (const float*)d_in[0];
    const int* A     = (const int*)d_in[1];
    const int* lens  = (const int*)d_in[2];
    const float* alp = (const float*)d_in[3];
    const float* Wq  = (const float*)d_in[4];
    const float* bq  = (const float*)d_in[5];
    const float* Wk  = (const float*)d_in[6];
    const float* bk  = (const float*)d_in[7];
    const float* Wv  = (const float*)d_in[8];
    const float* bv  = (const float*)d_in[9];

    float* outF = (float*)d_out;

    const size_t qkv = (size_t)BB * HH * NN * DD;
    float* Qw = (float*)d_ws;
    float* Kw = Qw + qkv;
    float* Vw = Kw + qkv;
    unsigned char* A8 = (unsigned char*)(Vw + qkv);
    double* sums = (double*)(A8 + (size_t)BB * NN * NN);
    unsigned long long* cnt = (unsigned long long*)(sums + 128);

    // zero sums[128] + cnt[64]
    (void)hipMemsetAsync(sums, 0, 128 * sizeof(double) + 64 * sizeof(unsigned long long), stream);

    proj_kernel<<<dim3(12, 128), 256, 0, stream>>>(h, Wq, bq, Wk, bk, Wv, bv, lens, Qw, Kw, Vw);
    pack_kernel<<<1024, 256, 0, stream>>>(A, A8, cnt);
    attn_kernel<<<BB * HH * (NN / QT), 256, 0, stream>>>(Qw, Kw, Vw, A8, lens, alp, outF, sums);
    fin_kernel<<<1, 64, 0, stream>>>(sums, cnt, outF + qkv);
}